// Round 4
// baseline (1096.953 us; speedup 1.0000x reference)
//
#include <hip/hip_runtime.h>
#include <hip/hip_bf16.h>
#include <math.h>

// Problem constants (from reference: 51^3 nodes, avg degree 64)
constexpr int N_NODES = 51 * 51 * 51;        // 132651
constexpr int N_EDGES = N_NODES * 64;        // 8489664
constexpr int E_HALF  = N_EDGES / 2;         // 4244832
constexpr int NP      = (N_NODES + 255) & ~255;  // padded node count

// Scatter partitioning: f32 accumulators, 144 KB LDS
constexpr int PART_S = 36864;                 // 36864 * 4 B = 147456 B LDS
constexpr int NP_S   = 4;                     // 4 * 36864 >= N_NODES
// Degree partitioning: packed u16 counters, 2 per u32 word, same 144 KB LDS
constexpr int PART_D  = 73728;
constexpr int NP_D    = 2;
constexpr int WORDS_D = PART_D / 2;           // 36864 u32 words

// Output kernel: s staged as bf16 in LDS, 2 passes
constexpr int PART_O   = 73728;               // bf16 entries per pass (144 KB)
constexpr int NPASS_O  = 2;
constexpr int SBF_LEN  = PART_O * NPASS_O;    // 147456 (padded s_bf length)
constexpr int OUT_BLOCKS = 256;
constexpr int OUT_T    = OUT_BLOCKS * 1024;   // 262144 threads
constexpr int K_OUT    = (E_HALF + OUT_T - 1) / OUT_T;  // 17 outputs/thread

// ================= partitioned-LDS path (no global atomics) =================

// Pass A: degree histogram, packed u16 counters, depth-2 prefetch.
__global__ __launch_bounds__(1024) void k_deg_part(const int4* __restrict__ col4,
                                                   unsigned* __restrict__ partial,
                                                   int Bp) {
    __shared__ unsigned cnt[WORDS_D];
    const int p = blockIdx.x / Bp;
    const int b = blockIdx.x % Bp;
    const int base = p * PART_D;
    for (int j = threadIdx.x; j < WORDS_D; j += 1024) cnt[j] = 0u;
    __syncthreads();
    const int n4 = N_EDGES / 4;
    const int stride = Bp * 1024;
    int i = b * 1024 + threadIdx.x;
    bool valid = i < n4;
    int4 c;
    if (valid) c = col4[i];
    while (valid) {
        const int inext = i + stride;
        const bool vnext = inext < n4;
        int4 cn;
        if (vnext) cn = col4[inext];   // prefetch next tile before LDS work
        unsigned j;
        j = (unsigned)(c.x - base);
        if (j < (unsigned)PART_D) atomicAdd(&cnt[j >> 1], 1u << ((j & 1) << 4));
        j = (unsigned)(c.y - base);
        if (j < (unsigned)PART_D) atomicAdd(&cnt[j >> 1], 1u << ((j & 1) << 4));
        j = (unsigned)(c.z - base);
        if (j < (unsigned)PART_D) atomicAdd(&cnt[j >> 1], 1u << ((j & 1) << 4));
        j = (unsigned)(c.w - base);
        if (j < (unsigned)PART_D) atomicAdd(&cnt[j >> 1], 1u << ((j & 1) << 4));
        c = cn; i = inext; valid = vnext;
    }
    __syncthreads();
    unsigned* dst = partial + (size_t)blockIdx.x * WORDS_D;
    for (int j = threadIdx.x; j < WORDS_D; j += 1024) dst[j] = cnt[j];
}

// Reduce A: deg[v] = 1 + sum_b cnt;  dinv = rsqrt(deg);  u = dinv * x.
__global__ __launch_bounds__(256) void k_reduceA(const unsigned* __restrict__ partial,
                                                 const float* __restrict__ x,
                                                 int Bp,
                                                 float* __restrict__ dinv,
                                                 float* __restrict__ u) {
    int v = blockIdx.x * 256 + threadIdx.x;
    if (v >= N_NODES) return;
    const int p = (v >= PART_D) ? 1 : 0;
    const int j = v - p * PART_D;
    const int word = j >> 1;
    const int sh = (j & 1) << 4;
    const unsigned* src = partial + (size_t)(p * Bp) * WORDS_D + word;
    unsigned deg = 1;  // self-loop
#pragma unroll 8
    for (int b = 0; b < Bp; ++b) deg += (src[(size_t)b * WORDS_D] >> sh) & 0xFFFFu;
    float d = rsqrtf((float)deg);
    dinv[v] = d;
    u[v] = d * x[v];
}

// Pass B: weighted scatter g[col] += u[row] via LDS float atomics, prefetched.
__global__ __launch_bounds__(1024) void k_scat_part(const int4* __restrict__ row4,
                                                    const int4* __restrict__ col4,
                                                    const float* __restrict__ u,
                                                    float* __restrict__ partial,
                                                    int Bp) {
    __shared__ float acc[PART_S];
    const int p = blockIdx.x / Bp;
    const int b = blockIdx.x % Bp;
    const int base = p * PART_S;
    for (int j = threadIdx.x; j < PART_S; j += 1024) acc[j] = 0.f;
    __syncthreads();
    const int n4 = N_EDGES / 4;
    const int stride = Bp * 1024;
    int i = b * 1024 + threadIdx.x;
    bool valid = i < n4;
    int4 c, r;
    if (valid) { c = col4[i]; r = row4[i]; }
    while (valid) {
        const int inext = i + stride;
        const bool vnext = inext < n4;
        int4 cn, rn;
        if (vnext) { cn = col4[inext]; rn = row4[inext]; }  // prefetch
        unsigned j;
        j = (unsigned)(c.x - base);
        if (j < (unsigned)PART_S) atomicAdd(&acc[j], u[r.x]);
        j = (unsigned)(c.y - base);
        if (j < (unsigned)PART_S) atomicAdd(&acc[j], u[r.y]);
        j = (unsigned)(c.z - base);
        if (j < (unsigned)PART_S) atomicAdd(&acc[j], u[r.z]);
        j = (unsigned)(c.w - base);
        if (j < (unsigned)PART_S) atomicAdd(&acc[j], u[r.w]);
        c = cn; r = rn; i = inext; valid = vnext;
    }
    __syncthreads();
    float* dst = partial + (size_t)blockIdx.x * PART_S;
    for (int j = threadIdx.x; j < PART_S; j += 1024) dst[j] = acc[j];
}

// Reduce B: t = dinv*(g+u);  s = relu(t*W0+b0) + relu(t*W1+b1), stored bf16.
__global__ __launch_bounds__(256) void k_reduceB(const float* __restrict__ partial,
                                                 const float* __restrict__ dinv,
                                                 const float* __restrict__ u,
                                                 const float* __restrict__ W,
                                                 const float* __restrict__ bb,
                                                 int Bp,
                                                 __hip_bfloat16* __restrict__ sbf) {
    int v = blockIdx.x * 256 + threadIdx.x;
    if (v >= N_NODES) return;
    const int p = (unsigned)v / (unsigned)PART_S;
    const int j = v - p * PART_S;
    const float* src = partial + (size_t)(p * Bp) * PART_S + j;
    float g = 0.f;
#pragma unroll 8
    for (int b = 0; b < Bp; ++b) g += src[(size_t)b * PART_S];
    float t = dinv[v] * (g + u[v]);
    float h0 = fmaxf(fmaf(t, W[0], bb[0]), 0.f);
    float h1 = fmaxf(fmaf(t, W[1], bb[1]), 0.f);
    sbf[v] = __float2bfloat16(h0 + h1);
}

// ================= fallback path (global atomics) =================

__global__ __launch_bounds__(256) void k_init_deg(int* __restrict__ deg) {
    int i = blockIdx.x * 256 + threadIdx.x;
    if (i < N_NODES) deg[i] = 1;
}

__global__ __launch_bounds__(256) void k_deg(const int4* __restrict__ col4,
                                             int* __restrict__ deg) {
    int i = blockIdx.x * 256 + threadIdx.x;
    const int stride = gridDim.x * 256;
    const int n4 = N_EDGES / 4;
    for (; i < n4; i += stride) {
        int4 c = col4[i];
        atomicAdd(&deg[c.x], 1); atomicAdd(&deg[c.y], 1);
        atomicAdd(&deg[c.z], 1); atomicAdd(&deg[c.w], 1);
    }
}

__global__ __launch_bounds__(256) void k_dinv(const int* __restrict__ deg,
                                              const float* __restrict__ x,
                                              float* __restrict__ dinv,
                                              float* __restrict__ t) {
    int i = blockIdx.x * 256 + threadIdx.x;
    if (i >= N_NODES) return;
    float d = rsqrtf((float)deg[i]);
    dinv[i] = d;
    t[i] = d * d * x[i];
}

__global__ __launch_bounds__(256) void k_scatter(const int4* __restrict__ row4,
                                                 const int4* __restrict__ col4,
                                                 const float* __restrict__ x,
                                                 const float* __restrict__ dinv,
                                                 float* __restrict__ t) {
    int i = blockIdx.x * 256 + threadIdx.x;
    const int stride = gridDim.x * 256;
    const int n4 = N_EDGES / 4;
    for (; i < n4; i += stride) {
        int4 r = row4[i];
        int4 c = col4[i];
        atomicAdd(&t[c.x], dinv[r.x] * dinv[c.x] * x[r.x]);
        atomicAdd(&t[c.y], dinv[r.y] * dinv[c.y] * x[r.y]);
        atomicAdd(&t[c.z], dinv[r.z] * dinv[c.z] * x[r.z]);
        atomicAdd(&t[c.w], dinv[r.w] * dinv[c.w] * x[r.w]);
    }
}

__global__ __launch_bounds__(256) void k_node(const float* __restrict__ t,
                                              const float* __restrict__ W,
                                              const float* __restrict__ b,
                                              __hip_bfloat16* __restrict__ sbf) {
    int i = blockIdx.x * 256 + threadIdx.x;
    if (i >= N_NODES) return;
    float tv = t[i];
    float h0 = fmaxf(fmaf(tv, W[0], b[0]), 0.f);
    float h1 = fmaxf(fmaf(tv, W[1], b[1]), 0.f);
    sbf[i] = __float2bfloat16(h0 + h1);
}

// ================= output kernel =================
// Indices held in registers (streamed once); s staged bf16 in LDS, 2 passes.
__global__ __launch_bounds__(1024) void k_out(const int* __restrict__ rowA,
                                              const int* __restrict__ colA,
                                              const int* __restrict__ rowB,
                                              const int* __restrict__ colB,
                                              const ushort* __restrict__ sbf,
                                              float* __restrict__ out) {
    __shared__ ushort sl[PART_O];
    const int t = blockIdx.x * 1024 + threadIdx.x;
    int ia[K_OUT], ib[K_OUT], ic[K_OUT], id[K_OUT];
    float y[K_OUT];
#pragma unroll
    for (int k = 0; k < K_OUT; ++k) {
        const int i = t + k * OUT_T;
        const bool v = i < E_HALF;
        ia[k] = v ? rowA[i] : -1;   // -1 never matches any partition
        ib[k] = v ? colA[i] : -1;
        ic[k] = v ? rowB[i] : -1;
        id[k] = v ? colB[i] : -1;
        y[k] = 0.f;
    }
    for (int p = 0; p < NPASS_O; ++p) {
        const int base = p * PART_O;
        __syncthreads();
        const uint4* src = (const uint4*)(sbf + base);
        uint4* dst = (uint4*)sl;
        for (int j = threadIdx.x; j < PART_O / 8; j += 1024) dst[j] = src[j];
        __syncthreads();
#pragma unroll
        for (int k = 0; k < K_OUT; ++k) {
            unsigned j;
            j = (unsigned)(ia[k] - base);
            if (j < (unsigned)PART_O) y[k] += __uint_as_float((unsigned)sl[j] << 16);
            j = (unsigned)(ib[k] - base);
            if (j < (unsigned)PART_O) y[k] += __uint_as_float((unsigned)sl[j] << 16);
            j = (unsigned)(ic[k] - base);
            if (j < (unsigned)PART_O) y[k] += __uint_as_float((unsigned)sl[j] << 16);
            j = (unsigned)(id[k] - base);
            if (j < (unsigned)PART_O) y[k] += __uint_as_float((unsigned)sl[j] << 16);
        }
    }
#pragma unroll
    for (int k = 0; k < K_OUT; ++k) {
        const int i = t + k * OUT_T;
        if (i < E_HALF) out[i] = 1.f / (1.f + __expf(-0.5f * y[k]));
    }
}

// ================= launch =================

extern "C" void kernel_launch(void* const* d_in, const int* in_sizes, int n_in,
                              void* d_out, int out_size, void* d_ws, size_t ws_size,
                              hipStream_t stream) {
    const float* x = (const float*)d_in[0];
    const float* W = (const float*)d_in[1];
    const float* b = (const float*)d_in[2];
    const int*   ei = (const int*)d_in[3];
    const int* row = ei;
    const int* col = ei + N_EDGES;
    float* out = (float*)d_out;

    char* ws = (char*)d_ws;
    float* dinv = (float*)(ws);                          // NP f32
    float* u    = (float*)(ws + (size_t)NP * 4);         // NP f32
    __hip_bfloat16* sbf = (__hip_bfloat16*)(ws + (size_t)NP * 8);  // SBF_LEN bf16
    char* partialBase = ws + (size_t)NP * 8 + (size_t)SBF_LEN * 2;
    size_t head = (size_t)NP * 8 + (size_t)SBF_LEN * 2;
    size_t avail = (ws_size > head) ? ws_size - head : 0;

    int Bp_d = (int)(avail / ((size_t)NP_D * WORDS_D * 4));  // per-block 294912 B
    if (Bp_d > 128) Bp_d = 128;
    int Bp_s = (int)(avail / ((size_t)NP_S * PART_S * 4));   // per-block 589824 B
    if (Bp_s > 64) Bp_s = 64;

    const int nodeBlocks = (N_NODES + 255) / 256;
    const int edgeBlocks = 2048;

    if (Bp_s >= 2 && Bp_d >= 2) {
        unsigned* partU = (unsigned*)partialBase;
        float*    partF = (float*)partialBase;  // reused after reduceA consumes partU
        k_deg_part<<<NP_D * Bp_d, 1024, 0, stream>>>((const int4*)col, partU, Bp_d);
        k_reduceA<<<nodeBlocks, 256, 0, stream>>>(partU, x, Bp_d, dinv, u);
        k_scat_part<<<NP_S * Bp_s, 1024, 0, stream>>>((const int4*)row, (const int4*)col,
                                                      u, partF, Bp_s);
        k_reduceB<<<nodeBlocks, 256, 0, stream>>>(partF, dinv, u, W, b, Bp_s, sbf);
    } else {
        int* deg = (int*)partialBase;  // fallback scratch
        k_init_deg<<<nodeBlocks, 256, 0, stream>>>(deg);
        k_deg<<<edgeBlocks, 256, 0, stream>>>((const int4*)col, deg);
        k_dinv<<<nodeBlocks, 256, 0, stream>>>(deg, x, dinv, u);
        k_scatter<<<edgeBlocks, 256, 0, stream>>>((const int4*)row, (const int4*)col,
                                                  x, dinv, u);
        k_node<<<nodeBlocks, 256, 0, stream>>>(u, W, b, sbf);
    }

    k_out<<<OUT_BLOCKS, 1024, 0, stream>>>(row, col, row + E_HALF, col + E_HALF,
                                           (const ushort*)sbf, out);
}

// Round 5
// 133.511 us; speedup vs baseline: 8.2162x; 8.2162x over previous
//
#include <hip/hip_runtime.h>
#include <hip/hip_bf16.h>
#include <math.h>

// Problem constants (from reference: 51^3 nodes, avg degree 64)
constexpr int N_NODES = 51 * 51 * 51;        // 132651
constexpr int N_EDGES = N_NODES * 64;        // 8489664
constexpr int E_HALF  = N_EDGES / 2;         // 4244832
constexpr int NP      = (N_NODES + 255) & ~255;  // padded node count

// Scatter partitioning: f32 accumulators, 144 KB LDS
constexpr int PART_S = 36864;                 // 36864 * 4 B = 147456 B LDS
constexpr int NP_S   = 4;                     // 4 * 36864 >= N_NODES
// Degree partitioning: packed u16 counters, 2 per u32 word, same 144 KB LDS
constexpr int PART_D  = 73728;
constexpr int NP_D    = 2;
constexpr int WORDS_D = PART_D / 2;           // 36864 u32 words

// Output kernel: s staged as bf16 in LDS, 2 pass-launches
constexpr int PART_O   = 73728;               // bf16 entries per pass (144 KB)
constexpr int NPASS_O  = 2;
constexpr int SBF_LEN  = PART_O * NPASS_O;    // 147456 (padded s_bf length)
constexpr int OUT_BLOCKS = 256;               // 1 block/CU (144 KB LDS)

// ================= partitioned-LDS path (no global atomics) =================

// Pass A: degree histogram, packed u16 counters, depth-2 prefetch.
__global__ __launch_bounds__(1024) void k_deg_part(const int4* __restrict__ col4,
                                                   unsigned* __restrict__ partial,
                                                   int Bp) {
    __shared__ unsigned cnt[WORDS_D];
    const int p = blockIdx.x / Bp;
    const int b = blockIdx.x % Bp;
    const int base = p * PART_D;
    for (int j = threadIdx.x; j < WORDS_D; j += 1024) cnt[j] = 0u;
    __syncthreads();
    const int n4 = N_EDGES / 4;
    const int stride = Bp * 1024;
    int i = b * 1024 + threadIdx.x;
    bool valid = i < n4;
    int4 c;
    if (valid) c = col4[i];
    while (valid) {
        const int inext = i + stride;
        const bool vnext = inext < n4;
        int4 cn;
        if (vnext) cn = col4[inext];   // prefetch next tile before LDS work
        unsigned j;
        j = (unsigned)(c.x - base);
        if (j < (unsigned)PART_D) atomicAdd(&cnt[j >> 1], 1u << ((j & 1) << 4));
        j = (unsigned)(c.y - base);
        if (j < (unsigned)PART_D) atomicAdd(&cnt[j >> 1], 1u << ((j & 1) << 4));
        j = (unsigned)(c.z - base);
        if (j < (unsigned)PART_D) atomicAdd(&cnt[j >> 1], 1u << ((j & 1) << 4));
        j = (unsigned)(c.w - base);
        if (j < (unsigned)PART_D) atomicAdd(&cnt[j >> 1], 1u << ((j & 1) << 4));
        c = cn; i = inext; valid = vnext;
    }
    __syncthreads();
    unsigned* dst = partial + (size_t)blockIdx.x * WORDS_D;
    for (int j = threadIdx.x; j < WORDS_D; j += 1024) dst[j] = cnt[j];
}

// Reduce A: deg[v] = 1 + sum_b cnt;  dinv = rsqrt(deg);  u = dinv * x.
__global__ __launch_bounds__(256) void k_reduceA(const unsigned* __restrict__ partial,
                                                 const float* __restrict__ x,
                                                 int Bp,
                                                 float* __restrict__ dinv,
                                                 float* __restrict__ u) {
    int v = blockIdx.x * 256 + threadIdx.x;
    if (v >= N_NODES) return;
    const int p = (v >= PART_D) ? 1 : 0;
    const int j = v - p * PART_D;
    const int word = j >> 1;
    const int sh = (j & 1) << 4;
    const unsigned* src = partial + (size_t)(p * Bp) * WORDS_D + word;
    unsigned deg = 1;  // self-loop
#pragma unroll 8
    for (int b = 0; b < Bp; ++b) deg += (src[(size_t)b * WORDS_D] >> sh) & 0xFFFFu;
    float d = rsqrtf((float)deg);
    dinv[v] = d;
    u[v] = d * x[v];
}

// Pass B: weighted scatter g[col] += u[row] via LDS float atomics, prefetched.
__global__ __launch_bounds__(1024) void k_scat_part(const int4* __restrict__ row4,
                                                    const int4* __restrict__ col4,
                                                    const float* __restrict__ u,
                                                    float* __restrict__ partial,
                                                    int Bp) {
    __shared__ float acc[PART_S];
    const int p = blockIdx.x / Bp;
    const int b = blockIdx.x % Bp;
    const int base = p * PART_S;
    for (int j = threadIdx.x; j < PART_S; j += 1024) acc[j] = 0.f;
    __syncthreads();
    const int n4 = N_EDGES / 4;
    const int stride = Bp * 1024;
    int i = b * 1024 + threadIdx.x;
    bool valid = i < n4;
    int4 c, r;
    if (valid) { c = col4[i]; r = row4[i]; }
    while (valid) {
        const int inext = i + stride;
        const bool vnext = inext < n4;
        int4 cn, rn;
        if (vnext) { cn = col4[inext]; rn = row4[inext]; }  // prefetch
        unsigned j;
        j = (unsigned)(c.x - base);
        if (j < (unsigned)PART_S) atomicAdd(&acc[j], u[r.x]);
        j = (unsigned)(c.y - base);
        if (j < (unsigned)PART_S) atomicAdd(&acc[j], u[r.y]);
        j = (unsigned)(c.z - base);
        if (j < (unsigned)PART_S) atomicAdd(&acc[j], u[r.z]);
        j = (unsigned)(c.w - base);
        if (j < (unsigned)PART_S) atomicAdd(&acc[j], u[r.w]);
        c = cn; r = rn; i = inext; valid = vnext;
    }
    __syncthreads();
    float* dst = partial + (size_t)blockIdx.x * PART_S;
    for (int j = threadIdx.x; j < PART_S; j += 1024) dst[j] = acc[j];
}

// Reduce B: t = dinv*(g+u);  s = relu(t*W0+b0) + relu(t*W1+b1), stored bf16.
__global__ __launch_bounds__(256) void k_reduceB(const float* __restrict__ partial,
                                                 const float* __restrict__ dinv,
                                                 const float* __restrict__ u,
                                                 const float* __restrict__ W,
                                                 const float* __restrict__ bb,
                                                 int Bp,
                                                 __hip_bfloat16* __restrict__ sbf) {
    int v = blockIdx.x * 256 + threadIdx.x;
    if (v >= N_NODES) return;
    const int p = (unsigned)v / (unsigned)PART_S;
    const int j = v - p * PART_S;
    const float* src = partial + (size_t)(p * Bp) * PART_S + j;
    float g = 0.f;
#pragma unroll 8
    for (int b = 0; b < Bp; ++b) g += src[(size_t)b * PART_S];
    float t = dinv[v] * (g + u[v]);
    float h0 = fmaxf(fmaf(t, W[0], bb[0]), 0.f);
    float h1 = fmaxf(fmaf(t, W[1], bb[1]), 0.f);
    sbf[v] = __float2bfloat16(h0 + h1);
}

// ================= fallback path (global atomics) =================

__global__ __launch_bounds__(256) void k_init_deg(int* __restrict__ deg) {
    int i = blockIdx.x * 256 + threadIdx.x;
    if (i < N_NODES) deg[i] = 1;
}

__global__ __launch_bounds__(256) void k_deg(const int4* __restrict__ col4,
                                             int* __restrict__ deg) {
    int i = blockIdx.x * 256 + threadIdx.x;
    const int stride = gridDim.x * 256;
    const int n4 = N_EDGES / 4;
    for (; i < n4; i += stride) {
        int4 c = col4[i];
        atomicAdd(&deg[c.x], 1); atomicAdd(&deg[c.y], 1);
        atomicAdd(&deg[c.z], 1); atomicAdd(&deg[c.w], 1);
    }
}

__global__ __launch_bounds__(256) void k_dinv(const int* __restrict__ deg,
                                              const float* __restrict__ x,
                                              float* __restrict__ dinv,
                                              float* __restrict__ t) {
    int i = blockIdx.x * 256 + threadIdx.x;
    if (i >= N_NODES) return;
    float d = rsqrtf((float)deg[i]);
    dinv[i] = d;
    t[i] = d * d * x[i];
}

__global__ __launch_bounds__(256) void k_scatter(const int4* __restrict__ row4,
                                                 const int4* __restrict__ col4,
                                                 const float* __restrict__ x,
                                                 const float* __restrict__ dinv,
                                                 float* __restrict__ t) {
    int i = blockIdx.x * 256 + threadIdx.x;
    const int stride = gridDim.x * 256;
    const int n4 = N_EDGES / 4;
    for (; i < n4; i += stride) {
        int4 r = row4[i];
        int4 c = col4[i];
        atomicAdd(&t[c.x], dinv[r.x] * dinv[c.x] * x[r.x]);
        atomicAdd(&t[c.y], dinv[r.y] * dinv[c.y] * x[r.y]);
        atomicAdd(&t[c.z], dinv[r.z] * dinv[c.z] * x[r.z]);
        atomicAdd(&t[c.w], dinv[r.w] * dinv[c.w] * x[r.w]);
    }
}

__global__ __launch_bounds__(256) void k_node(const float* __restrict__ t,
                                              const float* __restrict__ W,
                                              const float* __restrict__ b,
                                              __hip_bfloat16* __restrict__ sbf) {
    int i = blockIdx.x * 256 + threadIdx.x;
    if (i >= N_NODES) return;
    float tv = t[i];
    float h0 = fmaxf(fmaf(tv, W[0], b[0]), 0.f);
    float h1 = fmaxf(fmaf(tv, W[1], b[1]), 0.f);
    sbf[i] = __float2bfloat16(h0 + h1);
}

// ================= output kernel: 2 pass-launches, no persistent state ======

__device__ __forceinline__ float bf2f(ushort u) {
    return __uint_as_float((unsigned)u << 16);
}

// Stage one s-partition in LDS; grid-stride the edge list; accumulate the
// partition's contribution into out[] (f32 partial). Final pass adds and
// applies sigmoid. No per-thread arrays -> no spill (rule #20 post-mortem).
__global__ __launch_bounds__(1024) void k_out_pass(const int4* __restrict__ rowA4,
                                                   const int4* __restrict__ colA4,
                                                   const int4* __restrict__ rowB4,
                                                   const int4* __restrict__ colB4,
                                                   const ushort* __restrict__ sbf,
                                                   float4* __restrict__ out,
                                                   int base, int final_pass) {
    __shared__ ushort sl[PART_O];
    {
        const uint4* src = (const uint4*)(sbf + base);
        uint4* dst = (uint4*)sl;
        for (int j = threadIdx.x; j < PART_O / 8; j += 1024) dst[j] = src[j];
    }
    __syncthreads();
    const int n4 = E_HALF / 4;                 // 1061208
    const int stride = gridDim.x * 1024;
#pragma unroll 2
    for (int i = blockIdx.x * 1024 + threadIdx.x; i < n4; i += stride) {
        int4 ra = rowA4[i], ca = colA4[i], rb = rowB4[i], cb = colB4[i];
        float c0 = 0.f, c1 = 0.f, c2 = 0.f, c3 = 0.f;
        unsigned j;
        j = (unsigned)(ra.x - base); if (j < (unsigned)PART_O) c0 += bf2f(sl[j]);
        j = (unsigned)(ca.x - base); if (j < (unsigned)PART_O) c0 += bf2f(sl[j]);
        j = (unsigned)(rb.x - base); if (j < (unsigned)PART_O) c0 += bf2f(sl[j]);
        j = (unsigned)(cb.x - base); if (j < (unsigned)PART_O) c0 += bf2f(sl[j]);
        j = (unsigned)(ra.y - base); if (j < (unsigned)PART_O) c1 += bf2f(sl[j]);
        j = (unsigned)(ca.y - base); if (j < (unsigned)PART_O) c1 += bf2f(sl[j]);
        j = (unsigned)(rb.y - base); if (j < (unsigned)PART_O) c1 += bf2f(sl[j]);
        j = (unsigned)(cb.y - base); if (j < (unsigned)PART_O) c1 += bf2f(sl[j]);
        j = (unsigned)(ra.z - base); if (j < (unsigned)PART_O) c2 += bf2f(sl[j]);
        j = (unsigned)(ca.z - base); if (j < (unsigned)PART_O) c2 += bf2f(sl[j]);
        j = (unsigned)(rb.z - base); if (j < (unsigned)PART_O) c2 += bf2f(sl[j]);
        j = (unsigned)(cb.z - base); if (j < (unsigned)PART_O) c2 += bf2f(sl[j]);
        j = (unsigned)(ra.w - base); if (j < (unsigned)PART_O) c3 += bf2f(sl[j]);
        j = (unsigned)(ca.w - base); if (j < (unsigned)PART_O) c3 += bf2f(sl[j]);
        j = (unsigned)(rb.w - base); if (j < (unsigned)PART_O) c3 += bf2f(sl[j]);
        j = (unsigned)(cb.w - base); if (j < (unsigned)PART_O) c3 += bf2f(sl[j]);
        float4 o;
        if (final_pass) {
            float4 prev = out[i];
            o.x = 1.f / (1.f + __expf(-0.5f * (prev.x + c0)));
            o.y = 1.f / (1.f + __expf(-0.5f * (prev.y + c1)));
            o.z = 1.f / (1.f + __expf(-0.5f * (prev.z + c2)));
            o.w = 1.f / (1.f + __expf(-0.5f * (prev.w + c3)));
        } else {
            o.x = c0; o.y = c1; o.z = c2; o.w = c3;
        }
        out[i] = o;
    }
}

// ================= launch =================

extern "C" void kernel_launch(void* const* d_in, const int* in_sizes, int n_in,
                              void* d_out, int out_size, void* d_ws, size_t ws_size,
                              hipStream_t stream) {
    const float* x = (const float*)d_in[0];
    const float* W = (const float*)d_in[1];
    const float* b = (const float*)d_in[2];
    const int*   ei = (const int*)d_in[3];
    const int* row = ei;
    const int* col = ei + N_EDGES;
    float* out = (float*)d_out;

    char* ws = (char*)d_ws;
    float* dinv = (float*)(ws);                          // NP f32
    float* u    = (float*)(ws + (size_t)NP * 4);         // NP f32
    __hip_bfloat16* sbf = (__hip_bfloat16*)(ws + (size_t)NP * 8);  // SBF_LEN bf16
    char* partialBase = ws + (size_t)NP * 8 + (size_t)SBF_LEN * 2;
    size_t head = (size_t)NP * 8 + (size_t)SBF_LEN * 2;
    size_t avail = (ws_size > head) ? ws_size - head : 0;

    int Bp_d = (int)(avail / ((size_t)NP_D * WORDS_D * 4));  // per-block 294912 B
    if (Bp_d > 128) Bp_d = 128;
    int Bp_s = (int)(avail / ((size_t)NP_S * PART_S * 4));   // per-block 589824 B
    if (Bp_s > 64) Bp_s = 64;

    const int nodeBlocks = (N_NODES + 255) / 256;
    const int edgeBlocks = 2048;

    if (Bp_s >= 2 && Bp_d >= 2) {
        unsigned* partU = (unsigned*)partialBase;
        float*    partF = (float*)partialBase;  // reused after reduceA consumes partU
        k_deg_part<<<NP_D * Bp_d, 1024, 0, stream>>>((const int4*)col, partU, Bp_d);
        k_reduceA<<<nodeBlocks, 256, 0, stream>>>(partU, x, Bp_d, dinv, u);
        k_scat_part<<<NP_S * Bp_s, 1024, 0, stream>>>((const int4*)row, (const int4*)col,
                                                      u, partF, Bp_s);
        k_reduceB<<<nodeBlocks, 256, 0, stream>>>(partF, dinv, u, W, b, Bp_s, sbf);
    } else {
        int* deg = (int*)partialBase;  // fallback scratch
        k_init_deg<<<nodeBlocks, 256, 0, stream>>>(deg);
        k_deg<<<edgeBlocks, 256, 0, stream>>>((const int4*)col, deg);
        k_dinv<<<nodeBlocks, 256, 0, stream>>>(deg, x, dinv, u);
        k_scatter<<<edgeBlocks, 256, 0, stream>>>((const int4*)row, (const int4*)col,
                                                  x, dinv, u);
        k_node<<<nodeBlocks, 256, 0, stream>>>(u, W, b, sbf);
    }

    // Output: 2 pass-launches over the edge list, s staged bf16 in LDS.
    k_out_pass<<<OUT_BLOCKS, 1024, 0, stream>>>(
        (const int4*)row, (const int4*)col,
        (const int4*)(row + E_HALF), (const int4*)(col + E_HALF),
        (const ushort*)sbf, (float4*)out, 0, 0);
    k_out_pass<<<OUT_BLOCKS, 1024, 0, stream>>>(
        (const int4*)row, (const int4*)col,
        (const int4*)(row + E_HALF), (const int4*)(col + E_HALF),
        (const ushort*)sbf, (float4*)out, PART_O, 1);
}